// Round 2
// baseline (376.405 us; speedup 1.0000x reference)
//
#include <hip/hip_runtime.h>
#include <hip/hip_bf16.h>

#define BATCH 256
#define SEQ   512
#define DIM   128
#define LDSK  136   // padded LDS row stride in bf16 elems (272 B; 16B-aligned, 4-bank row shift)

typedef __attribute__((ext_vector_type(8))) __bf16  bf16x8;
typedef __attribute__((ext_vector_type(4))) __bf16  bf16x4;
typedef __attribute__((ext_vector_type(4))) float   f32x4;

// ---- B-fragment loaders: bf16 direct, or fp32 on-the-fly convert
__device__ __forceinline__ bf16x8 load_bfrag(const __bf16* __restrict__ wg, int n, int k0) {
  return *(const bf16x8*)(wg + n * DIM + k0);
}
__device__ __forceinline__ bf16x8 load_bfrag(const float* __restrict__ wg, int n, int k0) {
  const float4 v0 = *(const float4*)(wg + n * DIM + k0);
  const float4 v1 = *(const float4*)(wg + n * DIM + k0 + 4);
  bf16x8 r = { (__bf16)v0.x, (__bf16)v0.y, (__bf16)v0.z, (__bf16)v0.w,
               (__bf16)v1.x, (__bf16)v1.y, (__bf16)v1.z, (__bf16)v1.w };
  return r;
}

// ---- one layer's matmul: wave-private 16-row stripe, acc[8] covers all 128 cols
template<typename WT>
__device__ __forceinline__ void matmul_layer(
    const __bf16* __restrict__ Xa, const WT* __restrict__ wg,
    const float* __restrict__ bias, f32x4 (&acc)[8], int rowbase, int m, int q)
{
#pragma unroll
  for (int ct = 0; ct < 8; ++ct) {
    const float b = bias[ct * 16 + m];
    acc[ct] = (f32x4){b, b, b, b};
  }
#pragma unroll
  for (int ks = 0; ks < 4; ++ks) {
    const int k0 = ks * 32 + q * 8;
    const bf16x8 a = *(const bf16x8*)(Xa + (rowbase + m) * LDSK + k0);
#pragma unroll
    for (int ct = 0; ct < 8; ++ct) {
      const bf16x8 bw = load_bfrag(wg, ct * 16 + m, k0);
      acc[ct] = __builtin_amdgcn_mfma_f32_16x16x32_bf16(a, bw, acc[ct], 0, 0, 0);
    }
  }
}

__device__ __forceinline__ void stats_accum(
    const f32x4 (&acc)[8], float* sumA, float* sqA, int m, int q)
{
#pragma unroll
  for (int ct = 0; ct < 8; ++ct) {
    float s = 0.f, ss = 0.f;
#pragma unroll
    for (int r = 0; r < 4; ++r) { const float v = acc[ct][r]; s += v; ss += v * v; }
    s  += __shfl_xor(s, 16, 64);  s  += __shfl_xor(s, 32, 64);
    ss += __shfl_xor(ss, 16, 64); ss += __shfl_xor(ss, 32, 64);
    if (q == 0) { atomicAdd(&sumA[ct * 16 + m], s); atomicAdd(&sqA[ct * 16 + m], ss); }
  }
}

// per-lane BN coef computation (redundant across q-groups; removes a barrier) + relu + LDS store
__device__ __forceinline__ void bn_relu_store(
    const f32x4 (&acc)[8], __bf16* Xa, const float* sumA, const float* sqA,
    const float* __restrict__ g, const float* __restrict__ be,
    int rowbase, int m, int q)
{
#pragma unroll
  for (int ct = 0; ct < 8; ++ct) {
    const int n = ct * 16 + m;
    const float mean = sumA[n] * (1.0f / BATCH);
    const float var  = sqA[n]  * (1.0f / BATCH) - mean * mean;
    const float a = g[n] * rsqrtf(var + 1e-5f);
    const float c = be[n] - a * mean;
#pragma unroll
    for (int r = 0; r < 4; ++r) {
      const float y = fmaxf(0.f, a * acc[ct][r] + c);
      Xa[(rowbase + q * 4 + r) * LDSK + n] = (__bf16)y;
    }
  }
}

// ---------------- fused MLP: 1024 threads (16 waves), one WG = one 256x128 batch problem
// WT: weight element type. GATE: s-path (per-slice input, gated output). CONV: also
// convert 3 fp32 weight matrices to bf16 in ws (done by the c-kernel for the s-kernel).
template<typename WT, bool GATE, bool CONV>
__global__ __launch_bounds__(1024, 4)
void mlp_kernel(const float* __restrict__ xin, long xrow_stride,
                const WT* __restrict__ w1, const WT* __restrict__ w2, const WT* __restrict__ w3,
                const float* __restrict__ b1, const float* __restrict__ g1, const float* __restrict__ be1,
                const float* __restrict__ b2, const float* __restrict__ g2, const float* __restrict__ be2,
                const float* __restrict__ b3,
                const float* __restrict__ cw0, const float* __restrict__ cw1,
                const float* __restrict__ cw2, __bf16* __restrict__ cvt_dst,
                const float* __restrict__ gate,   // c_out [256*128] when GATE
                float* __restrict__ out)          // GATE: s_out base; else c_out (ws)
{
  const int tid  = threadIdx.x;
  const int wave = tid >> 6, lane = tid & 63;
  const int m = lane & 15, q = lane >> 4;
  const int rowbase = wave * 16;                  // 16 waves x 16 rows = 256
  const int slice = GATE ? blockIdx.x : 0;
  const float* x0 = GATE ? (xin + (long)slice * DIM) : xin;

  __shared__ __bf16 Xa[BATCH * LDSK];             // 69632 B
  __shared__ float sum0[DIM], sq0[DIM], sum1[DIM], sq1[DIM];

  if (CONV) {
    // fp32 -> bf16 for the s-kernel's 3 weight matrices (12288 float4 chunks)
    const float* srcs[3] = {cw0, cw1, cw2};
#pragma unroll
    for (int it = 0; it < 12; ++it) {
      const int ci = it * 1024 + tid;
      const int mi = ci >> 12;
      const int j  = (ci & 4095) * 4;
      const float4 v = *(const float4*)(srcs[mi] + j);
      bf16x4 h = { (__bf16)v.x, (__bf16)v.y, (__bf16)v.z, (__bf16)v.w };
      *(bf16x4*)(cvt_dst + mi * 16384 + j) = h;
    }
  }

  // stage own 16 rows -> LDS bf16 (per-instr: 16 lanes x 16B = 256B contiguous segments)
#pragma unroll
  for (int it = 0; it < 4; ++it) {
    const int row = rowbase + it * 4 + (lane >> 4);
    const int col = (lane & 15) * 8;
    const float* src = x0 + (long)row * xrow_stride + col;
    const float4 v0 = *(const float4*)src;
    const float4 v1 = *(const float4*)(src + 4);
    bf16x8 h = { (__bf16)v0.x, (__bf16)v0.y, (__bf16)v0.z, (__bf16)v0.w,
                 (__bf16)v1.x, (__bf16)v1.y, (__bf16)v1.z, (__bf16)v1.w };
    *(bf16x8*)(Xa + row * LDSK + col) = h;
  }
  if (tid < DIM) { sum0[tid] = 0.f; sq0[tid] = 0.f; sum1[tid] = 0.f; sq1[tid] = 0.f; }
  __syncthreads();   // stats zero visible (X is wave-private, needs no barrier)

  f32x4 acc[8];

  // Layer 1
  matmul_layer(Xa, w1, b1, acc, rowbase, m, q);
  stats_accum(acc, sum0, sq0, m, q);
  __syncthreads();
  bn_relu_store(acc, Xa, sum0, sq0, g1, be1, rowbase, m, q);

  // Layer 2 (stats into ping-pong set1; no barrier needed before — set1 untouched)
  matmul_layer(Xa, w2, b2, acc, rowbase, m, q);
  stats_accum(acc, sum1, sq1, m, q);
  __syncthreads();
  bn_relu_store(acc, Xa, sum1, sq1, g2, be2, rowbase, m, q);

  // Layer 3 + epilogue (no stats, no barrier)
  matmul_layer(Xa, w3, b3, acc, rowbase, m, q);

#pragma unroll
  for (int ct = 0; ct < 8; ++ct) {
    const int col = ct * 16 + m;
#pragma unroll
    for (int r = 0; r < 4; ++r) {
      const int row = rowbase + q * 4 + r;
      float y = acc[ct][r];
      if (GATE) {
        y *= gate[row * DIM + col];
        out[((long)row * SEQ + slice) * DIM + col] = y;
      } else {
        out[row * DIM + col] = y;
      }
    }
  }
}

__device__ __forceinline__ float4 vmax4(float4 a, float4 b) {
  return (float4){fmaxf(a.x, b.x), fmaxf(a.y, b.y), fmaxf(a.z, b.z), fmaxf(a.w, b.w)};
}

// ---------------- max over sequence axis: agg[b,d] = max_i s_out[b,i,d]
__global__ __launch_bounds__(512) void maxpool_kernel(
    const float* __restrict__ sout, float* __restrict__ agg)
{
  __shared__ float4 red[512];
  const int b = blockIdx.x;
  const int t = threadIdx.x;
  const int d4 = (t & 31) * 4;        // 32 threads cover 128 d as float4
  const int ig = t >> 5;              // 16 i-groups of 32
  const float* p = sout + (long)b * SEQ * DIM + d4;
  float4 m0 = {-INFINITY, -INFINITY, -INFINITY, -INFINITY};
  float4 m1 = m0;
  const int i0 = ig * 32;
#pragma unroll 8
  for (int i = i0; i < i0 + 32; i += 2) {
    m0 = vmax4(m0, *(const float4*)(p + (long)(i + 0) * DIM));
    m1 = vmax4(m1, *(const float4*)(p + (long)(i + 1) * DIM));
  }
  red[t] = vmax4(m0, m1);
  __syncthreads();
  if (t < 32) {
    float4 a = red[t];
#pragma unroll
    for (int g = 1; g < 16; ++g) a = vmax4(a, red[g * 32 + t]);
    *(float4*)(agg + b * DIM + t * 4) = a;
  }
}

extern "C" void kernel_launch(void* const* d_in, const int* in_sizes, int n_in,
                              void* d_out, int out_size, void* d_ws, size_t ws_size,
                              hipStream_t stream)
{
  const float* s     = (const float*)d_in[0];
  const float* c     = (const float*)d_in[1];
  const float* s_w1  = (const float*)d_in[2];
  const float* s_b1  = (const float*)d_in[3];
  const float* s_g1  = (const float*)d_in[4];
  const float* s_be1 = (const float*)d_in[5];
  const float* s_w2  = (const float*)d_in[6];
  const float* s_b2  = (const float*)d_in[7];
  const float* s_g2  = (const float*)d_in[8];
  const float* s_be2 = (const float*)d_in[9];
  const float* s_w3  = (const float*)d_in[10];
  const float* s_b3  = (const float*)d_in[11];
  const float* c_w1  = (const float*)d_in[12];
  const float* c_b1  = (const float*)d_in[13];
  const float* c_g1  = (const float*)d_in[14];
  const float* c_be1 = (const float*)d_in[15];
  const float* c_w2  = (const float*)d_in[16];
  const float* c_b2  = (const float*)d_in[17];
  const float* c_g2  = (const float*)d_in[18];
  const float* c_be2 = (const float*)d_in[19];
  const float* c_w3  = (const float*)d_in[20];
  const float* c_b3  = (const float*)d_in[21];

  float* out   = (float*)d_out;                          // s_out then aggregated
  float* c_out = (float*)d_ws;                           // 32768 floats
  __bf16* wbf  = (__bf16*)((char*)d_ws + (size_t)BATCH * DIM * sizeof(float));

  // 1) c-path MLP (fp32 weights on the fly) -> c_out; also converts s-weights -> wbf
  mlp_kernel<float, false, true><<<1, 1024, 0, stream>>>(
      c, (long)DIM,
      c_w1, c_w2, c_w3,
      c_b1, c_g1, c_be1, c_b2, c_g2, c_be2, c_b3,
      s_w1, s_w2, s_w3, wbf,
      nullptr, c_out);

  // 2) s-path MLP per slice, gated by c_out -> s_out
  mlp_kernel<__bf16, true, false><<<SEQ, 1024, 0, stream>>>(
      s, (long)SEQ * DIM,
      wbf, wbf + 16384, wbf + 2 * 16384,
      s_b1, s_g1, s_be1, s_b2, s_g2, s_be2, s_b3,
      nullptr, nullptr, nullptr, nullptr,
      c_out, out);

  // 3) aggregated = max over sequence axis
  maxpool_kernel<<<BATCH, 512, 0, stream>>>(out, out + (long)BATCH * SEQ * DIM);
}

// Round 3
// 268.916 us; speedup vs baseline: 1.3997x; 1.3997x over previous
//
#include <hip/hip_runtime.h>
#include <hip/hip_bf16.h>

#define BATCH 256
#define SEQ   512
#define DIM   128
#define LDSK  136   // padded LDS row stride in bf16 elems (272 B; 16B-aligned, 4-bank row shift)

typedef __attribute__((ext_vector_type(8))) __bf16  bf16x8;
typedef __attribute__((ext_vector_type(4))) __bf16  bf16x4;
typedef __attribute__((ext_vector_type(4))) float   f32x4;

// ---- one layer: acc[4][8] = X(wave's 64 rows) @ W^T + bias   (RT=4, round-1 proven)
__device__ __forceinline__ void matmul_layer(
    const __bf16* __restrict__ Xa, const __bf16* __restrict__ wg,
    const float* __restrict__ bias, f32x4 (&acc)[4][8], int rowbase, int m, int q)
{
#pragma unroll
  for (int ct = 0; ct < 8; ++ct) {
    const float b = bias[ct * 16 + m];
    const f32x4 bv = {b, b, b, b};
#pragma unroll
    for (int rt = 0; rt < 4; ++rt) acc[rt][ct] = bv;
  }
#pragma unroll
  for (int ks = 0; ks < 4; ++ks) {
    const int k0 = ks * 32 + q * 8;
    bf16x8 a[4], bw[8];
#pragma unroll
    for (int rt = 0; rt < 4; ++rt)
      a[rt] = *(const bf16x8*)(Xa + (rowbase + rt * 16 + m) * LDSK + k0);
#pragma unroll
    for (int ct = 0; ct < 8; ++ct)
      bw[ct] = *(const bf16x8*)(wg + (ct * 16 + m) * DIM + k0);
#pragma unroll
    for (int rt = 0; rt < 4; ++rt)
#pragma unroll
      for (int ct = 0; ct < 8; ++ct)
        acc[rt][ct] = __builtin_amdgcn_mfma_f32_16x16x32_bf16(a[rt], bw[ct], acc[rt][ct], 0, 0, 0);
  }
}

__device__ __forceinline__ void stats_accum(
    const f32x4 (&acc)[4][8], float* sumA, float* sqA, int m, int q)
{
#pragma unroll
  for (int ct = 0; ct < 8; ++ct) {
    float s = 0.f, ss = 0.f;
#pragma unroll
    for (int rt = 0; rt < 4; ++rt)
#pragma unroll
      for (int r = 0; r < 4; ++r) { const float v = acc[rt][ct][r]; s += v; ss += v * v; }
    s  += __shfl_xor(s, 16, 64);  s  += __shfl_xor(s, 32, 64);
    ss += __shfl_xor(ss, 16, 64); ss += __shfl_xor(ss, 32, 64);
    if (q == 0) { atomicAdd(&sumA[ct * 16 + m], s); atomicAdd(&sqA[ct * 16 + m], ss); }
  }
}

// per-lane redundant BN-coef computation (no coef barrier) + relu + wave-private LDS store
__device__ __forceinline__ void bn_relu_store(
    const f32x4 (&acc)[4][8], __bf16* Xa, const float* sumA, const float* sqA,
    const float* __restrict__ g, const float* __restrict__ be,
    int rowbase, int m, int q)
{
#pragma unroll
  for (int ct = 0; ct < 8; ++ct) {
    const int n = ct * 16 + m;
    const float mean = sumA[n] * (1.0f / BATCH);
    const float var  = sqA[n]  * (1.0f / BATCH) - mean * mean;
    const float a = g[n] * rsqrtf(var + 1e-5f);
    const float c = be[n] - a * mean;
#pragma unroll
    for (int rt = 0; rt < 4; ++rt)
#pragma unroll
      for (int r = 0; r < 4; ++r) {
        const float y = fmaxf(0.f, a * acc[rt][ct][r] + c);
        Xa[(rowbase + rt * 16 + q * 4 + r) * LDSK + n] = (__bf16)y;
      }
  }
}

// ---- one full 3-layer MLP phase. Staging and bn-stores are wave-private;
// only the two stats reductions need barriers.
__device__ __forceinline__ void run_phase(
    __bf16* Xa, const float* __restrict__ x0, long xstride,
    const __bf16* __restrict__ w1, const __bf16* __restrict__ w2, const __bf16* __restrict__ w3,
    const float* __restrict__ b1, const float* __restrict__ g1, const float* __restrict__ be1,
    const float* __restrict__ b2, const float* __restrict__ g2, const float* __restrict__ be2,
    const float* __restrict__ b3,
    float* st,   // 4*DIM floats: sum1,sq1,sum2,sq2 (pre-zeroed)
    int rowbase, int lane, int m, int q, f32x4 (&acc)[4][8])
{
  // stage this wave's 64 rows -> LDS bf16 (16 lanes x 32B = 512B per row, 4 rows/instr)
#pragma unroll
  for (int it = 0; it < 16; ++it) {
    const int row = rowbase + it * 4 + (lane >> 4);
    const int col = (lane & 15) * 8;
    const float* src = x0 + (long)row * xstride + col;
    const float4 v0 = *(const float4*)src;
    const float4 v1 = *(const float4*)(src + 4);
    bf16x8 h = { (__bf16)v0.x, (__bf16)v0.y, (__bf16)v0.z, (__bf16)v0.w,
                 (__bf16)v1.x, (__bf16)v1.y, (__bf16)v1.z, (__bf16)v1.w };
    *(bf16x8*)(Xa + row * LDSK + col) = h;
  }

  // Layer 1
  matmul_layer(Xa, w1, b1, acc, rowbase, m, q);
  stats_accum(acc, st, st + DIM, m, q);
  __syncthreads();
  bn_relu_store(acc, Xa, st, st + DIM, g1, be1, rowbase, m, q);

  // Layer 2
  matmul_layer(Xa, w2, b2, acc, rowbase, m, q);
  stats_accum(acc, st + 2 * DIM, st + 3 * DIM, m, q);
  __syncthreads();
  bn_relu_store(acc, Xa, st + 2 * DIM, st + 3 * DIM, g2, be2, rowbase, m, q);

  // Layer 3 (linear only; result left in acc)
  matmul_layer(Xa, w3, b3, acc, rowbase, m, q);
}

// ---------------- fused kernel: one WG = one s-slice; c-MLP computed redundantly
// per WG for its own rows (same 256x128 shape), gate applied at the store.
__global__ __launch_bounds__(256, 2)
void fused_kernel(const float* __restrict__ s, const float* __restrict__ c,
                  const __bf16* __restrict__ wbf,   // 6 x 128x128 bf16 (s_w1..3, c_w1..3)
                  const float* __restrict__ sb1, const float* __restrict__ sg1, const float* __restrict__ sbe1,
                  const float* __restrict__ sb2, const float* __restrict__ sg2, const float* __restrict__ sbe2,
                  const float* __restrict__ sb3,
                  const float* __restrict__ cb1, const float* __restrict__ cg1, const float* __restrict__ cbe1,
                  const float* __restrict__ cb2, const float* __restrict__ cg2, const float* __restrict__ cbe2,
                  const float* __restrict__ cb3,
                  float* __restrict__ out)
{
  const int tid  = threadIdx.x;
  const int wave = tid >> 6, lane = tid & 63;
  const int m = lane & 15, q = lane >> 4;
  const int rowbase = wave * 64;
  const int slice = blockIdx.x;

  __shared__ __bf16 Xa[BATCH * LDSK];     // 69632 B
  __shared__ float  sb[8 * DIM];          // c-L1,c-L2,s-L1,s-L2 (sum,sq each) = 4 KB

  for (int i = tid; i < 8 * DIM; i += 256) sb[i] = 0.f;
  __syncthreads();

  f32x4 acc[4][8];

  // ---- c-phase: this wave's 64 batch rows through the c-MLP
  run_phase(Xa, c, (long)DIM,
            wbf + 3 * 16384, wbf + 4 * 16384, wbf + 5 * 16384,
            cb1, cg1, cbe1, cb2, cg2, cbe2, cb3,
            sb, rowbase, lane, m, q, acc);

  // pack gate rows into bf16 VGPRs (64 regs); |out|<=~3.7 so bf16 gate is within budget
  bf16x4 cgate[4][8];
#pragma unroll
  for (int rt = 0; rt < 4; ++rt)
#pragma unroll
    for (int ct = 0; ct < 8; ++ct)
      cgate[rt][ct] = (bf16x4){ (__bf16)acc[rt][ct][0], (__bf16)acc[rt][ct][1],
                                (__bf16)acc[rt][ct][2], (__bf16)acc[rt][ct][3] };

  // ---- s-phase (no barrier needed at transition: Xa rows + stat buffers disjoint)
  run_phase(Xa, s + (long)slice * DIM, (long)SEQ * DIM,
            wbf, wbf + 16384, wbf + 2 * 16384,
            sb1, sg1, sbe1, sb2, sg2, sbe2, sb3,
            sb + 4 * DIM, rowbase, lane, m, q, acc);

  // ---- gated store
#pragma unroll
  for (int ct = 0; ct < 8; ++ct) {
    const int col = ct * 16 + m;
#pragma unroll
    for (int rt = 0; rt < 4; ++rt)
#pragma unroll
      for (int r = 0; r < 4; ++r) {
        const int row = rowbase + rt * 16 + q * 4 + r;
        const float y = acc[rt][ct][r] * (float)cgate[rt][ct][r];
        out[((long)row * SEQ + slice) * DIM + col] = y;
      }
  }
}

// ---------------- prep: fp32 weights -> bf16 in ws (6 x 128x128)
__global__ void prep_kernel(const float* __restrict__ w0, const float* __restrict__ w1,
                            const float* __restrict__ w2, const float* __restrict__ w3,
                            const float* __restrict__ w4, const float* __restrict__ w5,
                            __bf16* __restrict__ dst)
{
  const int idx = blockIdx.x * blockDim.x + threadIdx.x;   // 0..24575
  const int mi  = idx >> 12;
  const int j   = (idx & 4095) * 4;
  const float* srcs[6] = {w0, w1, w2, w3, w4, w5};
  const float4 v = *(const float4*)(srcs[mi] + j);
  bf16x4 h = { (__bf16)v.x, (__bf16)v.y, (__bf16)v.z, (__bf16)v.w };
  *(bf16x4*)(dst + mi * 16384 + j) = h;
}

__device__ __forceinline__ float4 vmax4(float4 a, float4 b) {
  return (float4){fmaxf(a.x, b.x), fmaxf(a.y, b.y), fmaxf(a.z, b.z), fmaxf(a.w, b.w)};
}

// ---------------- max over sequence: grid (256, 2); WG (b,h) covers 64 cols
__global__ __launch_bounds__(512) void maxpool_kernel(
    const float* __restrict__ sout, float* __restrict__ agg)
{
  __shared__ float4 red[512];
  const int b = blockIdx.x, h = blockIdx.y;
  const int t = threadIdx.x;
  const int dq = (t & 15) * 4 + h * 64;    // 16 col-quads x 4 = 64 cols
  const int ig = t >> 4;                   // 32 i-groups x 16 i
  const float* p = sout + (long)b * SEQ * DIM + dq;
  float4 m0 = {-INFINITY, -INFINITY, -INFINITY, -INFINITY};
  float4 m1 = m0;
  const int i0 = ig * 16;
#pragma unroll 8
  for (int i = i0; i < i0 + 16; i += 2) {
    m0 = vmax4(m0, *(const float4*)(p + (long)(i + 0) * DIM));
    m1 = vmax4(m1, *(const float4*)(p + (long)(i + 1) * DIM));
  }
  red[t] = vmax4(m0, m1);
  __syncthreads();
  if (t < 256) red[t] = vmax4(red[t], red[t + 256]);
  __syncthreads();
  if (t < 16) {
    float4 a = red[t];
#pragma unroll
    for (int g = 1; g < 16; ++g) a = vmax4(a, red[g * 16 + t]);
    *(float4*)(agg + b * DIM + dq) = a;
  }
}

extern "C" void kernel_launch(void* const* d_in, const int* in_sizes, int n_in,
                              void* d_out, int out_size, void* d_ws, size_t ws_size,
                              hipStream_t stream)
{
  const float* s     = (const float*)d_in[0];
  const float* c     = (const float*)d_in[1];
  const float* s_w1  = (const float*)d_in[2];
  const float* s_b1  = (const float*)d_in[3];
  const float* s_g1  = (const float*)d_in[4];
  const float* s_be1 = (const float*)d_in[5];
  const float* s_w2  = (const float*)d_in[6];
  const float* s_b2  = (const float*)d_in[7];
  const float* s_g2  = (const float*)d_in[8];
  const float* s_be2 = (const float*)d_in[9];
  const float* s_w3  = (const float*)d_in[10];
  const float* s_b3  = (const float*)d_in[11];
  const float* c_w1  = (const float*)d_in[12];
  const float* c_b1  = (const float*)d_in[13];
  const float* c_g1  = (const float*)d_in[14];
  const float* c_be1 = (const float*)d_in[15];
  const float* c_w2  = (const float*)d_in[16];
  const float* c_b2  = (const float*)d_in[17];
  const float* c_g2  = (const float*)d_in[18];
  const float* c_be2 = (const float*)d_in[19];
  const float* c_w3  = (const float*)d_in[20];
  const float* c_b3  = (const float*)d_in[21];

  float* out  = (float*)d_out;                 // s_out then aggregated
  __bf16* wbf = (__bf16*)d_ws;                 // 6 x 16384 bf16

  // 1) weights fp32 -> bf16 (s_w1,s_w2,s_w3,c_w1,c_w2,c_w3)
  prep_kernel<<<96, 256, 0, stream>>>(s_w1, s_w2, s_w3, c_w1, c_w2, c_w3, wbf);

  // 2) fused: per-WG c-MLP (gate in VGPRs) + s-MLP + gated store
  fused_kernel<<<SEQ, 256, 0, stream>>>(
      s, c, wbf,
      s_b1, s_g1, s_be1, s_b2, s_g2, s_be2, s_b3,
      c_b1, c_g1, c_be1, c_b2, c_g2, c_be2, c_b3,
      out);

  // 3) aggregated = max over sequence axis
  maxpool_kernel<<<dim3(BATCH, 2), 512, 0, stream>>>(out, out + (long)BATCH * SEQ * DIM);
}

// Round 4
// 254.268 us; speedup vs baseline: 1.4803x; 1.0576x over previous
//
#include <hip/hip_runtime.h>
#include <hip/hip_bf16.h>

#define BATCH 256
#define SEQ   512
#define DIM   128
#define LDSK  136   // padded LDS row stride in bf16 elems (272 B; 16B-aligned, 4-bank row shift)

typedef __attribute__((ext_vector_type(8))) __bf16  bf16x8;
typedef __attribute__((ext_vector_type(4))) __bf16  bf16x4;
typedef __attribute__((ext_vector_type(4))) float   f32x4;

// ---- one layer: acc[4][8] = X(wave's 64 rows) @ W^T + bias   (RT=4)
__device__ __forceinline__ void matmul_layer(
    const __bf16* __restrict__ Xa, const __bf16* __restrict__ wg,
    const float* __restrict__ bias, f32x4 (&acc)[4][8], int rowbase, int m, int q)
{
#pragma unroll
  for (int ct = 0; ct < 8; ++ct) {
    const float b = bias[ct * 16 + m];
    const f32x4 bv = {b, b, b, b};
#pragma unroll
    for (int rt = 0; rt < 4; ++rt) acc[rt][ct] = bv;
  }
#pragma unroll
  for (int ks = 0; ks < 4; ++ks) {
    const int k0 = ks * 32 + q * 8;
    bf16x8 a[4], bw[8];
#pragma unroll
    for (int rt = 0; rt < 4; ++rt)
      a[rt] = *(const bf16x8*)(Xa + (rowbase + rt * 16 + m) * LDSK + k0);
#pragma unroll
    for (int ct = 0; ct < 8; ++ct)
      bw[ct] = *(const bf16x8*)(wg + (ct * 16 + m) * DIM + k0);
#pragma unroll
    for (int rt = 0; rt < 4; ++rt)
#pragma unroll
      for (int ct = 0; ct < 8; ++ct)
        acc[rt][ct] = __builtin_amdgcn_mfma_f32_16x16x32_bf16(a[rt], bw[ct], acc[rt][ct], 0, 0, 0);
  }
}

__device__ __forceinline__ void stats_accum(
    const f32x4 (&acc)[4][8], float* sumA, float* sqA, int m, int q)
{
#pragma unroll
  for (int ct = 0; ct < 8; ++ct) {
    float s = 0.f, ss = 0.f;
#pragma unroll
    for (int rt = 0; rt < 4; ++rt)
#pragma unroll
      for (int r = 0; r < 4; ++r) { const float v = acc[rt][ct][r]; s += v; ss += v * v; }
    s  += __shfl_xor(s, 16, 64);  s  += __shfl_xor(s, 32, 64);
    ss += __shfl_xor(ss, 16, 64); ss += __shfl_xor(ss, 32, 64);
    if (q == 0) { atomicAdd(&sumA[ct * 16 + m], s); atomicAdd(&sqA[ct * 16 + m], ss); }
  }
}

// per-lane redundant BN-coef computation (no coef barrier) + relu + wave-private LDS store
__device__ __forceinline__ void bn_relu_store(
    const f32x4 (&acc)[4][8], __bf16* Xa, const float* sumA, const float* sqA,
    const float* __restrict__ g, const float* __restrict__ be,
    int rowbase, int m, int q)
{
#pragma unroll
  for (int ct = 0; ct < 8; ++ct) {
    const int n = ct * 16 + m;
    const float mean = sumA[n] * (1.0f / BATCH);
    const float var  = sqA[n]  * (1.0f / BATCH) - mean * mean;
    const float a = g[n] * rsqrtf(var + 1e-5f);
    const float c = be[n] - a * mean;
#pragma unroll
    for (int rt = 0; rt < 4; ++rt)
#pragma unroll
      for (int r = 0; r < 4; ++r) {
        const float y = fmaxf(0.f, a * acc[rt][ct][r] + c);
        Xa[(rowbase + rt * 16 + q * 4 + r) * LDSK + n] = (__bf16)y;
      }
  }
}

// ---- one full 3-layer MLP phase. Staging and bn-stores are wave-private;
// only the two stats reductions need barriers.
__device__ __forceinline__ void run_phase(
    __bf16* Xa, const float* __restrict__ x0, long xstride,
    const __bf16* __restrict__ w1, const __bf16* __restrict__ w2, const __bf16* __restrict__ w3,
    const float* __restrict__ b1, const float* __restrict__ g1, const float* __restrict__ be1,
    const float* __restrict__ b2, const float* __restrict__ g2, const float* __restrict__ be2,
    const float* __restrict__ b3,
    float* st,   // 4*DIM floats: sum1,sq1,sum2,sq2 (pre-zeroed)
    int rowbase, int lane, int m, int q, f32x4 (&acc)[4][8])
{
  // stage this wave's 64 rows -> LDS bf16 (16 lanes x 32B = 512B per row, 4 rows/instr)
#pragma unroll
  for (int it = 0; it < 16; ++it) {
    const int row = rowbase + it * 4 + (lane >> 4);
    const int col = (lane & 15) * 8;
    const float* src = x0 + (long)row * xstride + col;
    const float4 v0 = *(const float4*)src;
    const float4 v1 = *(const float4*)(src + 4);
    bf16x8 h = { (__bf16)v0.x, (__bf16)v0.y, (__bf16)v0.z, (__bf16)v0.w,
                 (__bf16)v1.x, (__bf16)v1.y, (__bf16)v1.z, (__bf16)v1.w };
    *(bf16x8*)(Xa + row * LDSK + col) = h;
  }

  // Layer 1
  matmul_layer(Xa, w1, b1, acc, rowbase, m, q);
  stats_accum(acc, st, st + DIM, m, q);
  __syncthreads();
  bn_relu_store(acc, Xa, st, st + DIM, g1, be1, rowbase, m, q);

  // Layer 2
  matmul_layer(Xa, w2, b2, acc, rowbase, m, q);
  stats_accum(acc, st + 2 * DIM, st + 3 * DIM, m, q);
  __syncthreads();
  bn_relu_store(acc, Xa, st + 2 * DIM, st + 3 * DIM, g2, be2, rowbase, m, q);

  // Layer 3 (linear only; result left in acc)
  matmul_layer(Xa, w3, b3, acc, rowbase, m, q);
}

// ---------------- fused kernel: one WG = one s-slice; c-MLP computed redundantly
// per WG for its own rows (same 256x128 shape), gate applied at the store.
// launch_bounds(256,1): allocator free to use the full unified VGPR/AGPR file
// (~230 regs live: acc 128 + cgate 64 + addressing). (256,2) capped at 128 and
// spilled ~110 MiB to scratch (round-3 WRITE_SIZE evidence). Occupancy is
// LDS-capped at 2 WG/CU either way (73.7 KB of 160 KB).
__global__ __launch_bounds__(256, 1)
void fused_kernel(const float* __restrict__ s, const float* __restrict__ c,
                  const __bf16* __restrict__ wbf,   // 6 x 128x128 bf16 (s_w1..3, c_w1..3)
                  const float* __restrict__ sb1, const float* __restrict__ sg1, const float* __restrict__ sbe1,
                  const float* __restrict__ sb2, const float* __restrict__ sg2, const float* __restrict__ sbe2,
                  const float* __restrict__ sb3,
                  const float* __restrict__ cb1, const float* __restrict__ cg1, const float* __restrict__ cbe1,
                  const float* __restrict__ cb2, const float* __restrict__ cg2, const float* __restrict__ cbe2,
                  const float* __restrict__ cb3,
                  float* __restrict__ out)
{
  const int tid  = threadIdx.x;
  const int wave = tid >> 6, lane = tid & 63;
  const int m = lane & 15, q = lane >> 4;
  const int rowbase = wave * 64;
  const int slice = blockIdx.x;

  __shared__ __bf16 Xa[BATCH * LDSK];     // 69632 B
  __shared__ float  sb[8 * DIM];          // c-L1,c-L2,s-L1,s-L2 (sum,sq each) = 4 KB

  for (int i = tid; i < 8 * DIM; i += 256) sb[i] = 0.f;
  __syncthreads();

  f32x4 acc[4][8];

  // ---- c-phase: this wave's 64 batch rows through the c-MLP
  run_phase(Xa, c, (long)DIM,
            wbf + 3 * 16384, wbf + 4 * 16384, wbf + 5 * 16384,
            cb1, cg1, cbe1, cb2, cg2, cbe2, cb3,
            sb, rowbase, lane, m, q, acc);

  // pack gate rows into bf16 VGPRs (64 regs); |out|<=~3.7 so bf16 gate is within budget
  bf16x4 cgate[4][8];
#pragma unroll
  for (int rt = 0; rt < 4; ++rt)
#pragma unroll
    for (int ct = 0; ct < 8; ++ct)
      cgate[rt][ct] = (bf16x4){ (__bf16)acc[rt][ct][0], (__bf16)acc[rt][ct][1],
                                (__bf16)acc[rt][ct][2], (__bf16)acc[rt][ct][3] };

  // ---- s-phase (no barrier needed at transition: Xa rows + stat buffers disjoint)
  run_phase(Xa, s + (long)slice * DIM, (long)SEQ * DIM,
            wbf, wbf + 16384, wbf + 2 * 16384,
            sb1, sg1, sbe1, sb2, sg2, sbe2, sb3,
            sb + 4 * DIM, rowbase, lane, m, q, acc);

  // ---- gated store
#pragma unroll
  for (int ct = 0; ct < 8; ++ct) {
    const int col = ct * 16 + m;
#pragma unroll
    for (int rt = 0; rt < 4; ++rt)
#pragma unroll
      for (int r = 0; r < 4; ++r) {
        const int row = rowbase + rt * 16 + q * 4 + r;
        const float y = acc[rt][ct][r] * (float)cgate[rt][ct][r];
        out[((long)row * SEQ + slice) * DIM + col] = y;
      }
  }
}

// ---------------- prep: fp32 weights -> bf16 in ws (6 x 128x128)
__global__ void prep_kernel(const float* __restrict__ w0, const float* __restrict__ w1,
                            const float* __restrict__ w2, const float* __restrict__ w3,
                            const float* __restrict__ w4, const float* __restrict__ w5,
                            __bf16* __restrict__ dst)
{
  const int idx = blockIdx.x * blockDim.x + threadIdx.x;   // 0..24575
  const int mi  = idx >> 12;
  const int j   = (idx & 4095) * 4;
  const float* srcs[6] = {w0, w1, w2, w3, w4, w5};
  const float4 v = *(const float4*)(srcs[mi] + j);
  bf16x4 h = { (__bf16)v.x, (__bf16)v.y, (__bf16)v.z, (__bf16)v.w };
  *(bf16x4*)(dst + mi * 16384 + j) = h;
}

__device__ __forceinline__ float4 vmax4(float4 a, float4 b) {
  return (float4){fmaxf(a.x, b.x), fmaxf(a.y, b.y), fmaxf(a.z, b.z), fmaxf(a.w, b.w)};
}

// ---------------- max over sequence: grid (256, 2); WG (b,h) covers 64 cols
__global__ __launch_bounds__(512) void maxpool_kernel(
    const float* __restrict__ sout, float* __restrict__ agg)
{
  __shared__ float4 red[512];
  const int b = blockIdx.x, h = blockIdx.y;
  const int t = threadIdx.x;
  const int dq = (t & 15) * 4 + h * 64;    // 16 col-quads x 4 = 64 cols
  const int ig = t >> 4;                   // 32 i-groups x 16 i
  const float* p = sout + (long)b * SEQ * DIM + dq;
  float4 m0 = {-INFINITY, -INFINITY, -INFINITY, -INFINITY};
  float4 m1 = m0;
  const int i0 = ig * 16;
#pragma unroll 8
  for (int i = i0; i < i0 + 16; i += 2) {
    m0 = vmax4(m0, *(const float4*)(p + (long)(i + 0) * DIM));
    m1 = vmax4(m1, *(const float4*)(p + (long)(i + 1) * DIM));
  }
  red[t] = vmax4(m0, m1);
  __syncthreads();
  if (t < 256) red[t] = vmax4(red[t], red[t + 256]);
  __syncthreads();
  if (t < 16) {
    float4 a = red[t];
#pragma unroll
    for (int g = 1; g < 16; ++g) a = vmax4(a, red[g * 16 + t]);
    *(float4*)(agg + b * DIM + dq) = a;
  }
}

extern "C" void kernel_launch(void* const* d_in, const int* in_sizes, int n_in,
                              void* d_out, int out_size, void* d_ws, size_t ws_size,
                              hipStream_t stream)
{
  const float* s     = (const float*)d_in[0];
  const float* c     = (const float*)d_in[1];
  const float* s_w1  = (const float*)d_in[2];
  const float* s_b1  = (const float*)d_in[3];
  const float* s_g1  = (const float*)d_in[4];
  const float* s_be1 = (const float*)d_in[5];
  const float* s_w2  = (const float*)d_in[6];
  const float* s_b2  = (const float*)d_in[7];
  const float* s_g2  = (const float*)d_in[8];
  const float* s_be2 = (const float*)d_in[9];
  const float* s_w3  = (const float*)d_in[10];
  const float* s_b3  = (const float*)d_in[11];
  const float* c_w1  = (const float*)d_in[12];
  const float* c_b1  = (const float*)d_in[13];
  const float* c_g1  = (const float*)d_in[14];
  const float* c_be1 = (const float*)d_in[15];
  const float* c_w2  = (const float*)d_in[16];
  const float* c_b2  = (const float*)d_in[17];
  const float* c_g2  = (const float*)d_in[18];
  const float* c_be2 = (const float*)d_in[19];
  const float* c_w3  = (const float*)d_in[20];
  const float* c_b3  = (const float*)d_in[21];

  float* out  = (float*)d_out;                 // s_out then aggregated
  __bf16* wbf = (__bf16*)d_ws;                 // 6 x 16384 bf16

  // 1) weights fp32 -> bf16 (s_w1,s_w2,s_w3,c_w1,c_w2,c_w3)
  prep_kernel<<<96, 256, 0, stream>>>(s_w1, s_w2, s_w3, c_w1, c_w2, c_w3, wbf);

  // 2) fused: per-WG c-MLP (gate in VGPRs) + s-MLP + gated store
  fused_kernel<<<SEQ, 256, 0, stream>>>(
      s, c, wbf,
      s_b1, s_g1, s_be1, s_b2, s_g2, s_be2, s_b3,
      c_b1, c_g1, c_be1, c_b2, c_g2, c_be2, c_b3,
      out);

  // 3) aggregated = max over sequence axis
  maxpool_kernel<<<dim3(BATCH, 2), 512, 0, stream>>>(out, out + (long)BATCH * SEQ * DIM);
}